// Round 14
// baseline (81.216 us; speedup 1.0000x reference)
//
#include <hip/hip_runtime.h>
#include <hip/hip_bf16.h>

typedef __attribute__((ext_vector_type(8))) short short8;
typedef __attribute__((ext_vector_type(4))) float f32x4;

// ---- geometry ----
// x,y: (1,32,36,48,48) f32.  conv 3x3x3 SAME -> unfold P=9 -> t (32,1024,81)
// res_trans: a = LeakyReLU(t @ (W2@W1)^T)   (81x81 collapsed matrix M)
// att: (1/81) * a @ b^T per channel -> (1,32,1024,1024) f32
// K padded 81 -> 96 in t/a/b buffers.
//
// LEDGER: conv co-split +7; rt 1024-regrid +3.1; att NT stores +14.6;
// (256,1) 0; conv kd-split -6.5; conv XCD swz 0; setup f4 + conv epi-split
// -0.5; rt->att fusion +2.1; att B-panel LDS share -1.4. Best = 78.2 (R13).
// This round: (1) setup ushort8 xt stores (write-side G13: 2B scalar -> 16B
// vector, full-line 1KB/wave bursts); (2) att T14 split -- issue A-fragment
// loads BEFORE staging+barrier; the compiler's vmcnt(0) drain at s_barrier
// guarantees A in registers when MFMAs start (kills post-barrier L2 chain).

static __device__ __forceinline__ unsigned short f2bf(float f) {
    unsigned int u = __float_as_uint(f);
    unsigned int r = (u + 0x7fffu + ((u >> 16) & 1u)) >> 16;
    return (unsigned short)r;
}

// ---------------- setup: transpose+pad, M=W2@W1, weight rearrange, t-pads ----
// blocks [0,3800)    : tx  (img,dd,hh) rows of xt, halo rows zeroed
// blocks [3800,3836) : M = W2@W1 -> bf16 96x96 (pad zeroed)
// blocks [3836,4052) : Wbf[img][tap(27)][co(32)][ci(32)]
// blocks [4052,4308) : zero pad columns 81..95 of tbuf rows
__global__ __launch_bounds__(256) void setup_kernel(
    const float* __restrict__ x, const float* __restrict__ y,
    const float* __restrict__ W1, const float* __restrict__ W2,
    const float* __restrict__ Wx, const float* __restrict__ Wy,
    unsigned short* __restrict__ xt, unsigned short* __restrict__ Mo,
    unsigned short* __restrict__ Wbf, unsigned short* __restrict__ tbuf) {
    int bb = blockIdx.x, tid = threadIdx.x;
    if (bb < 3800) {
        int img = bb / 1900, rr = bb % 1900;
        int dd = rr / 50, hh = rr % 50;
        unsigned short* dst = xt + img*(38*50*50*32) + (dd*50 + hh)*(50*32);
        if (dd >= 1 && dd <= 36 && hh >= 1 && hh <= 48) {
            __shared__ unsigned short lds[48*33];
            int d = dd - 1, h = hh - 1;
            const float* src = img ? y : x;
            for (int i = tid; i < 384; i += 256) {  // 384 = 32ci x 12 float4
                int ci = i / 12, w4 = (i % 12) * 4;
                float4 v = *reinterpret_cast<const float4*>(
                    &src[((ci*36 + d)*48 + h)*48 + w4]);
                lds[(w4+0)*33 + ci] = f2bf(v.x);
                lds[(w4+1)*33 + ci] = f2bf(v.y);
                lds[(w4+2)*33 + ci] = f2bf(v.z);
                lds[(w4+3)*33 + ci] = f2bf(v.w);
            }
            __syncthreads();
            // 1600 shorts = 200 ushort8 chunks; chunk ch covers wp=ch/4,
            // ci=(ch%4)*8..+7  (wp 0 and 49 are the zero w-pads)
            if (tid < 200) {
                int wp = tid >> 2, ci0 = (tid & 3) * 8;
                short8 v;
                if (wp == 0 || wp == 49) {
                    v = (short8){0,0,0,0,0,0,0,0};
                } else {
                    #pragma unroll
                    for (int j = 0; j < 8; ++j)
                        v[j] = (short)lds[(wp-1)*33 + ci0 + j];
                }
                *reinterpret_cast<short8*>(&dst[wp*32 + ci0]) = v;
            }
        } else {
            if (tid < 200)
                *reinterpret_cast<short8*>(&dst[tid*8]) = (short8){0,0,0,0,0,0,0,0};
        }
    } else if (bb < 3836) {
        int gid = (bb - 3800)*256 + tid;            // 9216 = 96*96
        int o = gid / 96, p = gid % 96;
        float v = 0.f;
        if (o < 81 && p < 81) {
            for (int k = 0; k < 162; ++k) v += W2[o*162 + k] * W1[k*81 + p];
        }
        Mo[o*96 + p] = f2bf(v);
    } else if (bb < 4052) {
        int e = (bb - 3836)*256 + tid;              // 2*27*32*32 = 55296
        if (e < 2*27*32*32) {
            int ci  = e % 32;
            int co  = (e / 32) % 32;
            int tap = (e / 1024) % 27;
            int img = e / 27648;
            const float* src = img ? Wy : Wx;
            Wbf[e] = f2bf(src[co*864 + ci*27 + tap]);
        }
    } else {
        int row = (bb - 4052)*256 + tid;            // 65536 rows of tbuf
        unsigned short* tr = tbuf + row*96 + 81;
        #pragma unroll
        for (int j = 0; j < 15; ++j) tr[j] = 0;
    }
}

// ---------------- conv (implicit GEMM, kd split across 3 waves) --------------
// grid 1728 = img(2) x d(36) x hpair(24), XCD-chunk-swizzled; block = 3 waves
// (kd 0..2). Epilogue 3-way: finalizer(u) = u>>2; each wave deposits its 8
// non-finalized units (24KB LDS), finalizes 4 units (16 stores).
__global__ __launch_bounds__(192, 1) void conv_kernel(
    const unsigned short* __restrict__ xt,
    const float* __restrict__ bx, const float* __restrict__ by,
    const unsigned short* __restrict__ Wbf, unsigned short* __restrict__ tbuf) {
    __shared__ __align__(16) float red[2][12][64][4];   // 24576 B
    int b = blockIdx.x;
    int wg = (b & 7) * 216 + (b >> 3);   // bijective XCD chunking: 1728 = 8*216
    int img = wg / 864; int rr = wg % 864;
    int d0 = rr / 24; int hp = rr % 24;
    int tid = threadIdx.x, kd = tid >> 6, lane = tid & 63;
    int r16 = lane & 15, g4 = lane >> 4;
    int hbase = hp*2;
    const unsigned short* Ximg = xt + img*(38*50*50*32);
    const unsigned short* Wimg = Wbf + img*(27*32*32);
    const float* bias = img ? by : bx;

    f32x4 acc[2][3][2];                  // [co-tile][w-tile][hh]
    #pragma unroll
    for (int i = 0; i < 2; ++i)
        #pragma unroll
        for (int j = 0; j < 3; ++j)
            #pragma unroll
            for (int k = 0; k < 2; ++k) acc[i][j][k] = (f32x4){0.f, 0.f, 0.f, 0.f};

    // this wave's kd-plane weight fragments
    short8 wf[3][3][2];
    #pragma unroll
    for (int kh = 0; kh < 3; ++kh)
        #pragma unroll
        for (int kw = 0; kw < 3; ++kw)
            #pragma unroll
            for (int ct = 0; ct < 2; ++ct)
                wf[kh][kw][ct] = *reinterpret_cast<const short8*>(
                    Wimg + (((kd*3 + kh)*3 + kw)*32 + ct*16 + r16)*32 + 8*g4);

    #pragma unroll
    for (int r = 0; r < 4; ++r) {    // xt rows hbase+0..hbase+3 (halo incl.)
        const unsigned short* xrow = Ximg + ((d0 + kd)*50 + (hbase + r))*(50*32);
        #pragma unroll
        for (int kw = 0; kw < 3; ++kw) {
            short8 bfr[3];
            #pragma unroll
            for (int wt = 0; wt < 3; ++wt)
                bfr[wt] = *reinterpret_cast<const short8*>(xrow + (wt*16 + r16 + kw)*32 + 8*g4);
            #pragma unroll
            for (int hh = 0; hh < 2; ++hh) {
                int kh = r - hh;
                if (kh >= 0 && kh < 3) {
                    #pragma unroll
                    for (int wt = 0; wt < 3; ++wt) {
                        acc[0][wt][hh] = __builtin_amdgcn_mfma_f32_16x16x32_bf16(wf[kh][kw][0], bfr[wt], acc[0][wt][hh], 0, 0, 0);
                        acc[1][wt][hh] = __builtin_amdgcn_mfma_f32_16x16x32_bf16(wf[kh][kw][1], bfr[wt], acc[1][wt][hh], 0, 0, 0);
                    }
                }
            }
        }
    }

    // deposit: each wave writes the 8 units it does NOT finalize.
    #pragma unroll
    for (int ct = 0; ct < 2; ++ct)
        #pragma unroll
        for (int wt = 0; wt < 3; ++wt)
            #pragma unroll
            for (int hh = 0; hh < 2; ++hh) {
                int u = (ct*3 + wt)*2 + hh;
                int f = u >> 2;
                if (f != kd) {
                    int j = (kd - f + 2) % 3;
                    *reinterpret_cast<f32x4*>(&red[j][u][lane][0]) = acc[ct][wt][hh];
                }
            }
    __syncthreads();

    // finalize my 4 units (compile-time ct/wt/hh per branch; kd wave-uniform)
    int l_hi = (d0/9)*256, p_hi = (d0%9)*9;
    unsigned short* tb = tbuf + img*(32*1024*96);
#define FIN(U, CT, WT, HH) { \
    f32x4 s = acc[CT][WT][HH] \
            + *reinterpret_cast<const f32x4*>(&red[0][U][lane][0]) \
            + *reinterpret_cast<const f32x4*>(&red[1][U][lane][0]); \
    int h = hbase + HH; \
    _Pragma("unroll") \
    for (int r = 0; r < 4; ++r) { \
        int co = CT*16 + g4*4 + r; \
        int w  = WT*16 + r16; \
        float v = s[r] + bias[co]; \
        int hw = h*48 + w; \
        int l = l_hi + hw/9, p = p_hi + hw%9; \
        tb[(co*1024 + l)*96 + p] = f2bf(v); \
    } }
    if (kd == 0)      { FIN(0,0,0,0) FIN(1,0,0,1) FIN(2,0,1,0)  FIN(3,0,1,1)  }
    else if (kd == 1) { FIN(4,0,2,0) FIN(5,0,2,1) FIN(6,1,0,0)  FIN(7,1,0,1)  }
    else              { FIN(8,1,1,0) FIN(9,1,1,1) FIN(10,1,2,0) FIN(11,1,2,1) }
#undef FIN
}

// ---------------- res_trans: a = LeakyReLU(t @ M^T), per (img,c) -------------
__global__ __launch_bounds__(256, 1) void rt_kernel(const unsigned short* __restrict__ tbuf,
                                                    const unsigned short* __restrict__ Mo,
                                                    unsigned short* __restrict__ ab) {
    int b = blockIdx.x;
    int img = b >> 7, c = (b >> 2) & 31, mc = b & 3;
    int tid = threadIdx.x, wv = tid >> 6, lane = tid & 63;
    int r16 = lane & 15, g4 = lane >> 4;

    short8 Bf[3][6];
    #pragma unroll
    for (int ks = 0; ks < 3; ++ks)
        #pragma unroll
        for (int n = 0; n < 6; ++n)
            Bf[ks][n] = *reinterpret_cast<const short8*>(Mo + (n*16 + r16)*96 + ks*32 + 8*g4);

    const unsigned short* tc = tbuf + (img*32 + c)*(1024*96);
    unsigned short*       oc = ab   + (img*32 + c)*(1024*96);
    for (int q = 0; q < 4; ++q) {
        int rowb = (mc*16 + wv*4 + q) * 16;
        f32x4 acc[6];
        #pragma unroll
        for (int n = 0; n < 6; ++n) acc[n] = (f32x4){0.f, 0.f, 0.f, 0.f};
        #pragma unroll
        for (int ks = 0; ks < 3; ++ks) {
            short8 Af = *reinterpret_cast<const short8*>(tc + (rowb + r16)*96 + ks*32 + 8*g4);
            #pragma unroll
            for (int n = 0; n < 6; ++n)
                acc[n] = __builtin_amdgcn_mfma_f32_16x16x32_bf16(Af, Bf[ks][n], acc[n], 0, 0, 0);
        }
        #pragma unroll
        for (int n = 0; n < 6; ++n)
            #pragma unroll
            for (int r = 0; r < 4; ++r) {
                int row = rowb + g4*4 + r;
                float v = acc[n][r];
                v = v > 0.f ? v : 0.2f*v;
                oc[row*96 + n*16 + r16] = f2bf(v);
            }
    }
}

// ---------------- att: out = (1/81) a @ b^T per channel ----------------------
// XCD-swizzled; B-panel staged in LDS once per block (R13 win). A-fragment
// loads issued BEFORE staging+barrier (T14): the vmcnt(0) drain at the
// barrier completes them into registers -> MFMAs start stall-free.
#define PST 104
__global__ __launch_bounds__(256) void att_kernel(const unsigned short* __restrict__ ab,
                                                  float* __restrict__ out) {
    __shared__ __align__(16) unsigned short b_lds[128][PST];
    int bid = blockIdx.x;
    int b = (bid & 7) * 256 + (bid >> 3);   // bijective: 2048 = 8 * 256
    int c = b >> 6, ty = (b >> 3) & 7, tx = b & 7;
    int tid = threadIdx.x, wv = tid >> 6, lane = tid & 63;
    int r16 = lane & 15, g4 = lane >> 4;
    const unsigned short* arow = ab + c*(1024*96);
    const unsigned short* brow = ab + (32 + c)*(1024*96);
    int rb = ty*128 + wv*32;
    int cb = tx*128;

    // T14: issue A loads first (6 x 16B per thread, 24 VGPR held)
    short8 A0[3], A1[3];
    #pragma unroll
    for (int ks = 0; ks < 3; ++ks) {
        A0[ks] = *reinterpret_cast<const short8*>(arow + (rb +      r16)*96 + ks*32 + 8*g4);
        A1[ks] = *reinterpret_cast<const short8*>(arow + (rb + 16 + r16)*96 + ks*32 + 8*g4);
    }

    // stage b-panel rows [cb, cb+128) x 96 cols -> LDS (1536 16B chunks)
    #pragma unroll
    for (int it = 0; it < 6; ++it) {
        int ch = tid + 256*it;
        int row = ch / 12, cj = ch % 12;
        *reinterpret_cast<short8*>(&b_lds[row][cj*8]) =
            *reinterpret_cast<const short8*>(brow + (cb + row)*96 + cj*8);
    }
    __syncthreads();

    f32x4 acc[2][8];
    #pragma unroll
    for (int m = 0; m < 2; ++m)
        #pragma unroll
        for (int n = 0; n < 8; ++n) acc[m][n] = (f32x4){0.f, 0.f, 0.f, 0.f};

    #pragma unroll
    for (int ks = 0; ks < 3; ++ks) {
        #pragma unroll
        for (int n = 0; n < 8; ++n) {
            short8 Bf = *reinterpret_cast<const short8*>(&b_lds[n*16 + r16][ks*32 + 8*g4]);
            acc[0][n] = __builtin_amdgcn_mfma_f32_16x16x32_bf16(A0[ks], Bf, acc[0][n], 0, 0, 0);
            acc[1][n] = __builtin_amdgcn_mfma_f32_16x16x32_bf16(A1[ks], Bf, acc[1][n], 0, 0, 0);
        }
    }
    const float s = 1.f / 81.f;
    #pragma unroll
    for (int mt = 0; mt < 2; ++mt)
        #pragma unroll
        for (int n = 0; n < 8; ++n)
            #pragma unroll
            for (int r = 0; r < 4; ++r) {
                int row = rb + mt*16 + g4*4 + r;
                int col = cb + n*16 + r16;
                out[(c*1024 + row)*1024 + col] = acc[mt][n][r] * s;
            }
}
#undef PST

extern "C" void kernel_launch(void* const* d_in, const int* in_sizes, int n_in,
                              void* d_out, int out_size, void* d_ws, size_t ws_size,
                              hipStream_t stream) {
    const float* x  = (const float*)d_in[0];
    const float* y  = (const float*)d_in[1];
    const float* Wx = (const float*)d_in[2];
    const float* bx = (const float*)d_in[3];
    const float* Wy = (const float*)d_in[4];
    const float* by = (const float*)d_in[5];
    const float* W1 = (const float*)d_in[6];
    const float* W2 = (const float*)d_in[7];
    (void)in_sizes; (void)n_in; (void)out_size; (void)ws_size;

    // workspace plan (total 25.30 MB):
    //  [0, 12582912)            xt (12.16 MB, dead after conv) then abuf (12.58 MB)
    //  [12582912, 25165824)     tbuf (12.58 MB)
    //  [25165824, 25184256)     Mo
    //  [25184256, 25294848)     Wbf
    char* ws = (char*)d_ws;
    unsigned short* xt   = (unsigned short*)(ws);
    unsigned short* abuf = (unsigned short*)(ws);
    unsigned short* tbuf = (unsigned short*)(ws + 12582912);
    unsigned short* Mo   = (unsigned short*)(ws + 25165824);
    unsigned short* Wbf  = (unsigned short*)(ws + 25184256);
    float* out = (float*)d_out;

    setup_kernel<<<4308, 256, 0, stream>>>(x, y, W1, W2, Wx, Wy, xt, Mo, Wbf, tbuf);
    conv_kernel<<<1728, 192, 0, stream>>>(xt, bx, by, Wbf, tbuf);
    rt_kernel<<<256, 256, 0, stream>>>(tbuf, Mo, abuf);
    att_kernel<<<2048, 256, 0, stream>>>(abuf, out);
}

// Round 15
// 77.962 us; speedup vs baseline: 1.0417x; 1.0417x over previous
//
#include <hip/hip_runtime.h>
#include <hip/hip_bf16.h>

typedef __attribute__((ext_vector_type(8))) short short8;
typedef __attribute__((ext_vector_type(4))) float f32x4;

// ---- geometry ----
// x,y: (1,32,36,48,48) f32.  conv 3x3x3 SAME -> unfold P=9 -> t (32,1024,81)
// res_trans: a = LeakyReLU(t @ (W2@W1)^T)   (81x81 collapsed matrix M)
// att: (1/81) * a @ b^T per channel -> (1,32,1024,1024) f32
// K padded 81 -> 96 in t/a/b buffers.
//
// LEDGER: conv co-split +7; rt 1024-regrid +3.1; att NT stores +14.6;
// (256,1) 0; conv kd-split -6.5; conv XCD swz 0; setup f4 + conv epi-split
// -0.5; rt->att fusion +2.1; att B-panel LDS share -1.4; att T14 A-preload
// (+setup v8 bundle) +3.0 -- T14 held 48 VGPR across the barrier, breaking
// att's 6-blocks/CU occupancy (R12 lesson: att is occupancy-sensitive).
// Best = 78.2 (R13). This round: att reverted to R13 exactly; setup keeps
// the ushort8 stores (isolating the R14 bundle).

static __device__ __forceinline__ unsigned short f2bf(float f) {
    unsigned int u = __float_as_uint(f);
    unsigned int r = (u + 0x7fffu + ((u >> 16) & 1u)) >> 16;
    return (unsigned short)r;
}

// ---------------- setup: transpose+pad, M=W2@W1, weight rearrange, t-pads ----
// blocks [0,3800)    : tx  (img,dd,hh) rows of xt, halo rows zeroed
// blocks [3800,3836) : M = W2@W1 -> bf16 96x96 (pad zeroed)
// blocks [3836,4052) : Wbf[img][tap(27)][co(32)][ci(32)]
// blocks [4052,4308) : zero pad columns 81..95 of tbuf rows
__global__ __launch_bounds__(256) void setup_kernel(
    const float* __restrict__ x, const float* __restrict__ y,
    const float* __restrict__ W1, const float* __restrict__ W2,
    const float* __restrict__ Wx, const float* __restrict__ Wy,
    unsigned short* __restrict__ xt, unsigned short* __restrict__ Mo,
    unsigned short* __restrict__ Wbf, unsigned short* __restrict__ tbuf) {
    int bb = blockIdx.x, tid = threadIdx.x;
    if (bb < 3800) {
        int img = bb / 1900, rr = bb % 1900;
        int dd = rr / 50, hh = rr % 50;
        unsigned short* dst = xt + img*(38*50*50*32) + (dd*50 + hh)*(50*32);
        if (dd >= 1 && dd <= 36 && hh >= 1 && hh <= 48) {
            __shared__ unsigned short lds[48*33];
            int d = dd - 1, h = hh - 1;
            const float* src = img ? y : x;
            for (int i = tid; i < 384; i += 256) {  // 384 = 32ci x 12 float4
                int ci = i / 12, w4 = (i % 12) * 4;
                float4 v = *reinterpret_cast<const float4*>(
                    &src[((ci*36 + d)*48 + h)*48 + w4]);
                lds[(w4+0)*33 + ci] = f2bf(v.x);
                lds[(w4+1)*33 + ci] = f2bf(v.y);
                lds[(w4+2)*33 + ci] = f2bf(v.z);
                lds[(w4+3)*33 + ci] = f2bf(v.w);
            }
            __syncthreads();
            // 1600 shorts = 200 ushort8 chunks; chunk ch covers wp=ch/4,
            // ci=(ch%4)*8..+7  (wp 0 and 49 are the zero w-pads)
            if (tid < 200) {
                int wp = tid >> 2, ci0 = (tid & 3) * 8;
                short8 v;
                if (wp == 0 || wp == 49) {
                    v = (short8){0,0,0,0,0,0,0,0};
                } else {
                    #pragma unroll
                    for (int j = 0; j < 8; ++j)
                        v[j] = (short)lds[(wp-1)*33 + ci0 + j];
                }
                *reinterpret_cast<short8*>(&dst[wp*32 + ci0]) = v;
            }
        } else {
            if (tid < 200)
                *reinterpret_cast<short8*>(&dst[tid*8]) = (short8){0,0,0,0,0,0,0,0};
        }
    } else if (bb < 3836) {
        int gid = (bb - 3800)*256 + tid;            // 9216 = 96*96
        int o = gid / 96, p = gid % 96;
        float v = 0.f;
        if (o < 81 && p < 81) {
            for (int k = 0; k < 162; ++k) v += W2[o*162 + k] * W1[k*81 + p];
        }
        Mo[o*96 + p] = f2bf(v);
    } else if (bb < 4052) {
        int e = (bb - 3836)*256 + tid;              // 2*27*32*32 = 55296
        if (e < 2*27*32*32) {
            int ci  = e % 32;
            int co  = (e / 32) % 32;
            int tap = (e / 1024) % 27;
            int img = e / 27648;
            const float* src = img ? Wy : Wx;
            Wbf[e] = f2bf(src[co*864 + ci*27 + tap]);
        }
    } else {
        int row = (bb - 4052)*256 + tid;            // 65536 rows of tbuf
        unsigned short* tr = tbuf + row*96 + 81;
        #pragma unroll
        for (int j = 0; j < 15; ++j) tr[j] = 0;
    }
}

// ---------------- conv (implicit GEMM, kd split across 3 waves) --------------
// grid 1728 = img(2) x d(36) x hpair(24), XCD-chunk-swizzled; block = 3 waves
// (kd 0..2). Epilogue 3-way: finalizer(u) = u>>2; each wave deposits its 8
// non-finalized units (24KB LDS), finalizes 4 units (16 stores).
__global__ __launch_bounds__(192, 1) void conv_kernel(
    const unsigned short* __restrict__ xt,
    const float* __restrict__ bx, const float* __restrict__ by,
    const unsigned short* __restrict__ Wbf, unsigned short* __restrict__ tbuf) {
    __shared__ __align__(16) float red[2][12][64][4];   // 24576 B
    int b = blockIdx.x;
    int wg = (b & 7) * 216 + (b >> 3);   // bijective XCD chunking: 1728 = 8*216
    int img = wg / 864; int rr = wg % 864;
    int d0 = rr / 24; int hp = rr % 24;
    int tid = threadIdx.x, kd = tid >> 6, lane = tid & 63;
    int r16 = lane & 15, g4 = lane >> 4;
    int hbase = hp*2;
    const unsigned short* Ximg = xt + img*(38*50*50*32);
    const unsigned short* Wimg = Wbf + img*(27*32*32);
    const float* bias = img ? by : bx;

    f32x4 acc[2][3][2];                  // [co-tile][w-tile][hh]
    #pragma unroll
    for (int i = 0; i < 2; ++i)
        #pragma unroll
        for (int j = 0; j < 3; ++j)
            #pragma unroll
            for (int k = 0; k < 2; ++k) acc[i][j][k] = (f32x4){0.f, 0.f, 0.f, 0.f};

    // this wave's kd-plane weight fragments
    short8 wf[3][3][2];
    #pragma unroll
    for (int kh = 0; kh < 3; ++kh)
        #pragma unroll
        for (int kw = 0; kw < 3; ++kw)
            #pragma unroll
            for (int ct = 0; ct < 2; ++ct)
                wf[kh][kw][ct] = *reinterpret_cast<const short8*>(
                    Wimg + (((kd*3 + kh)*3 + kw)*32 + ct*16 + r16)*32 + 8*g4);

    #pragma unroll
    for (int r = 0; r < 4; ++r) {    // xt rows hbase+0..hbase+3 (halo incl.)
        const unsigned short* xrow = Ximg + ((d0 + kd)*50 + (hbase + r))*(50*32);
        #pragma unroll
        for (int kw = 0; kw < 3; ++kw) {
            short8 bfr[3];
            #pragma unroll
            for (int wt = 0; wt < 3; ++wt)
                bfr[wt] = *reinterpret_cast<const short8*>(xrow + (wt*16 + r16 + kw)*32 + 8*g4);
            #pragma unroll
            for (int hh = 0; hh < 2; ++hh) {
                int kh = r - hh;
                if (kh >= 0 && kh < 3) {
                    #pragma unroll
                    for (int wt = 0; wt < 3; ++wt) {
                        acc[0][wt][hh] = __builtin_amdgcn_mfma_f32_16x16x32_bf16(wf[kh][kw][0], bfr[wt], acc[0][wt][hh], 0, 0, 0);
                        acc[1][wt][hh] = __builtin_amdgcn_mfma_f32_16x16x32_bf16(wf[kh][kw][1], bfr[wt], acc[1][wt][hh], 0, 0, 0);
                    }
                }
            }
        }
    }

    // deposit: each wave writes the 8 units it does NOT finalize.
    #pragma unroll
    for (int ct = 0; ct < 2; ++ct)
        #pragma unroll
        for (int wt = 0; wt < 3; ++wt)
            #pragma unroll
            for (int hh = 0; hh < 2; ++hh) {
                int u = (ct*3 + wt)*2 + hh;
                int f = u >> 2;
                if (f != kd) {
                    int j = (kd - f + 2) % 3;
                    *reinterpret_cast<f32x4*>(&red[j][u][lane][0]) = acc[ct][wt][hh];
                }
            }
    __syncthreads();

    // finalize my 4 units (compile-time ct/wt/hh per branch; kd wave-uniform)
    int l_hi = (d0/9)*256, p_hi = (d0%9)*9;
    unsigned short* tb = tbuf + img*(32*1024*96);
#define FIN(U, CT, WT, HH) { \
    f32x4 s = acc[CT][WT][HH] \
            + *reinterpret_cast<const f32x4*>(&red[0][U][lane][0]) \
            + *reinterpret_cast<const f32x4*>(&red[1][U][lane][0]); \
    int h = hbase + HH; \
    _Pragma("unroll") \
    for (int r = 0; r < 4; ++r) { \
        int co = CT*16 + g4*4 + r; \
        int w  = WT*16 + r16; \
        float v = s[r] + bias[co]; \
        int hw = h*48 + w; \
        int l = l_hi + hw/9, p = p_hi + hw%9; \
        tb[(co*1024 + l)*96 + p] = f2bf(v); \
    } }
    if (kd == 0)      { FIN(0,0,0,0) FIN(1,0,0,1) FIN(2,0,1,0)  FIN(3,0,1,1)  }
    else if (kd == 1) { FIN(4,0,2,0) FIN(5,0,2,1) FIN(6,1,0,0)  FIN(7,1,0,1)  }
    else              { FIN(8,1,1,0) FIN(9,1,1,1) FIN(10,1,2,0) FIN(11,1,2,1) }
#undef FIN
}

// ---------------- res_trans: a = LeakyReLU(t @ M^T), per (img,c) -------------
__global__ __launch_bounds__(256, 1) void rt_kernel(const unsigned short* __restrict__ tbuf,
                                                    const unsigned short* __restrict__ Mo,
                                                    unsigned short* __restrict__ ab) {
    int b = blockIdx.x;
    int img = b >> 7, c = (b >> 2) & 31, mc = b & 3;
    int tid = threadIdx.x, wv = tid >> 6, lane = tid & 63;
    int r16 = lane & 15, g4 = lane >> 4;

    short8 Bf[3][6];
    #pragma unroll
    for (int ks = 0; ks < 3; ++ks)
        #pragma unroll
        for (int n = 0; n < 6; ++n)
            Bf[ks][n] = *reinterpret_cast<const short8*>(Mo + (n*16 + r16)*96 + ks*32 + 8*g4);

    const unsigned short* tc = tbuf + (img*32 + c)*(1024*96);
    unsigned short*       oc = ab   + (img*32 + c)*(1024*96);
    for (int q = 0; q < 4; ++q) {
        int rowb = (mc*16 + wv*4 + q) * 16;
        f32x4 acc[6];
        #pragma unroll
        for (int n = 0; n < 6; ++n) acc[n] = (f32x4){0.f, 0.f, 0.f, 0.f};
        #pragma unroll
        for (int ks = 0; ks < 3; ++ks) {
            short8 Af = *reinterpret_cast<const short8*>(tc + (rowb + r16)*96 + ks*32 + 8*g4);
            #pragma unroll
            for (int n = 0; n < 6; ++n)
                acc[n] = __builtin_amdgcn_mfma_f32_16x16x32_bf16(Af, Bf[ks][n], acc[n], 0, 0, 0);
        }
        #pragma unroll
        for (int n = 0; n < 6; ++n)
            #pragma unroll
            for (int r = 0; r < 4; ++r) {
                int row = rowb + g4*4 + r;
                float v = acc[n][r];
                v = v > 0.f ? v : 0.2f*v;
                oc[row*96 + n*16 + r16] = f2bf(v);
            }
    }
}

// ---------------- att: out = (1/81) a @ b^T per channel ----------------------
// XCD-swizzled (channel tiles share an XCD L2). B-panel staged in LDS once
// per block (R13 win). A fragments loaded inline (R13 form -- T14 preload
// regressed: +48 held VGPR broke 6-blocks/CU occupancy).
#define PST 104
__global__ __launch_bounds__(256) void att_kernel(const unsigned short* __restrict__ ab,
                                                  float* __restrict__ out) {
    __shared__ __align__(16) unsigned short b_lds[128][PST];
    int bid = blockIdx.x;
    int b = (bid & 7) * 256 + (bid >> 3);   // bijective: 2048 = 8 * 256
    int c = b >> 6, ty = (b >> 3) & 7, tx = b & 7;
    int tid = threadIdx.x, wv = tid >> 6, lane = tid & 63;
    int r16 = lane & 15, g4 = lane >> 4;
    const unsigned short* arow = ab + c*(1024*96);
    const unsigned short* brow = ab + (32 + c)*(1024*96);
    int rb = ty*128 + wv*32;
    int cb = tx*128;

    // stage b-panel rows [cb, cb+128) x 96 cols -> LDS (1536 16B chunks)
    #pragma unroll
    for (int it = 0; it < 6; ++it) {
        int ch = tid + 256*it;
        int row = ch / 12, cj = ch % 12;
        *reinterpret_cast<short8*>(&b_lds[row][cj*8]) =
            *reinterpret_cast<const short8*>(brow + (cb + row)*96 + cj*8);
    }
    __syncthreads();

    f32x4 acc[2][8];
    #pragma unroll
    for (int m = 0; m < 2; ++m)
        #pragma unroll
        for (int n = 0; n < 8; ++n) acc[m][n] = (f32x4){0.f, 0.f, 0.f, 0.f};

    #pragma unroll
    for (int ks = 0; ks < 3; ++ks) {
        short8 A0 = *reinterpret_cast<const short8*>(arow + (rb +      r16)*96 + ks*32 + 8*g4);
        short8 A1 = *reinterpret_cast<const short8*>(arow + (rb + 16 + r16)*96 + ks*32 + 8*g4);
        #pragma unroll
        for (int n = 0; n < 8; ++n) {
            short8 Bf = *reinterpret_cast<const short8*>(&b_lds[n*16 + r16][ks*32 + 8*g4]);
            acc[0][n] = __builtin_amdgcn_mfma_f32_16x16x32_bf16(A0, Bf, acc[0][n], 0, 0, 0);
            acc[1][n] = __builtin_amdgcn_mfma_f32_16x16x32_bf16(A1, Bf, acc[1][n], 0, 0, 0);
        }
    }
    const float s = 1.f / 81.f;
    #pragma unroll
    for (int mt = 0; mt < 2; ++mt)
        #pragma unroll
        for (int n = 0; n < 8; ++n)
            #pragma unroll
            for (int r = 0; r < 4; ++r) {
                int row = rb + mt*16 + g4*4 + r;
                int col = cb + n*16 + r16;
                out[(c*1024 + row)*1024 + col] = acc[mt][n][r] * s;
            }
}
#undef PST

extern "C" void kernel_launch(void* const* d_in, const int* in_sizes, int n_in,
                              void* d_out, int out_size, void* d_ws, size_t ws_size,
                              hipStream_t stream) {
    const float* x  = (const float*)d_in[0];
    const float* y  = (const float*)d_in[1];
    const float* Wx = (const float*)d_in[2];
    const float* bx = (const float*)d_in[3];
    const float* Wy = (const float*)d_in[4];
    const float* by = (const float*)d_in[5];
    const float* W1 = (const float*)d_in[6];
    const float* W2 = (const float*)d_in[7];
    (void)in_sizes; (void)n_in; (void)out_size; (void)ws_size;

    // workspace plan (total 25.30 MB):
    //  [0, 12582912)            xt (12.16 MB, dead after conv) then abuf (12.58 MB)
    //  [12582912, 25165824)     tbuf (12.58 MB)
    //  [25165824, 25184256)     Mo
    //  [25184256, 25294848)     Wbf
    char* ws = (char*)d_ws;
    unsigned short* xt   = (unsigned short*)(ws);
    unsigned short* abuf = (unsigned short*)(ws);
    unsigned short* tbuf = (unsigned short*)(ws + 12582912);
    unsigned short* Mo   = (unsigned short*)(ws + 25165824);
    unsigned short* Wbf  = (unsigned short*)(ws + 25184256);
    float* out = (float*)d_out;

    setup_kernel<<<4308, 256, 0, stream>>>(x, y, W1, W2, Wx, Wy, xt, Mo, Wbf, tbuf);
    conv_kernel<<<1728, 192, 0, stream>>>(xt, bx, by, Wbf, tbuf);
    rt_kernel<<<256, 256, 0, stream>>>(tbuf, Mo, abuf);
    att_kernel<<<2048, 256, 0, stream>>>(abuf, out);
}